// Round 8
// baseline (95.087 us; speedup 1.0000x reference)
//
#include <hip/hip_runtime.h>
#include <hip/hip_cooperative_groups.h>
#include <math.h>

namespace cg = cooperative_groups;

// Forward kinematics as an associative scan over affine pairs (M, p):
//   elem_j = (R_j, l_j * R_j[:,2]);  (M1,p1) ⊗ (M2,p2) = (M1*M2, p1 + M1*p2)
// Output_i = p-component of inclusive prefix up to i.
//
// R7: ONE cooperative kernel. fold + wave shuffle scan (pe kept in regs) ->
// publish 48B block aggregate -> grid.sync -> redundant per-block ordered
// G-reduce of preceding aggregates (L2/LLC) -> apply -> single out write.
// Removes the q round-trip (24MB) and one launch gap vs R6. Custom ~2ulp
// inline sincos (Cody-Waite FMA + cephes polys) replaces ocml sincosf.
// Fallback: R6's two-kernel path if cooperative launch fails.

#define TPB 256
#define EPT 4
#define EPB (TPB * EPT)            // 1024 elements per block
#define MAXB 1024                  // blocks for N = 2^20
#define NWAVE (TPB / 64)

// fallback K1 config
#define K1_TPB 512
#define K1_EPT 2
#define K1_EPB (K1_TPB * K1_EPT)
#define K1_NW (K1_TPB / 64)

struct Xf {
    float m[9];  // row-major 3x3
    float p[3];
};

__device__ __forceinline__ void xf_identity(Xf& x) {
    x.m[0] = 1.f; x.m[1] = 0.f; x.m[2] = 0.f;
    x.m[3] = 0.f; x.m[4] = 1.f; x.m[5] = 0.f;
    x.m[6] = 0.f; x.m[7] = 0.f; x.m[8] = 1.f;
    x.p[0] = 0.f; x.p[1] = 0.f; x.p[2] = 0.f;
}

// out = A ⊗ B  (A is the earlier prefix)
__device__ __forceinline__ Xf xf_comb(const Xf& A, const Xf& B) {
    Xf o;
#pragma unroll
    for (int r = 0; r < 3; ++r) {
        const float a0 = A.m[r * 3 + 0], a1 = A.m[r * 3 + 1], a2 = A.m[r * 3 + 2];
#pragma unroll
        for (int c = 0; c < 3; ++c) {
            o.m[r * 3 + c] = a0 * B.m[0 * 3 + c] + a1 * B.m[1 * 3 + c] + a2 * B.m[2 * 3 + c];
        }
        o.p[r] = A.p[r] + a0 * B.p[0] + a1 * B.p[1] + a2 * B.p[2];
    }
    return o;
}

// ---- fast ~2ulp sincos, valid |x| <= ~12 (theta ~ N(0,1)) ----
// Cody-Waite 2-term FMA reduction (pi/2 = hi + mid), cephes minimax polys,
// branchless quadrant select via sign-bit XOR.
__device__ __forceinline__ void fast_sincos(float x, float& s, float& c) {
    const float fn = __builtin_rintf(x * 0.636619772367581343f);  // 2/pi
    const int n = (int)fn;
    float r = __builtin_fmaf(fn, -1.57079637050628662109375f, x); // -pio2_hi
    r = __builtin_fmaf(fn, 4.37113900018624283e-8f, r);           // -pio2_mid
    const float r2 = r * r;
    float sp = __builtin_fmaf(r2, -1.9515295891e-4f, 8.3321608736e-3f);
    sp = __builtin_fmaf(r2, sp, -1.6666654611e-1f);
    const float ss = __builtin_fmaf(r * r2, sp, r);               // sin(r)
    float cp = __builtin_fmaf(r2, 2.443315711809948e-5f, -1.388731625493765e-3f);
    cp = __builtin_fmaf(r2, cp, 4.166664568298827e-2f);
    const float cc = __builtin_fmaf(r2 * r2, cp,
                                    __builtin_fmaf(r2, -0.5f, 1.0f));  // cos(r)
    const int q = n & 3;
    const float s0 = (q & 1) ? cc : ss;
    const float c0 = (q & 1) ? ss : cc;
    const unsigned sgn_s = (unsigned)(q & 2) << 30;
    const unsigned sgn_c = (unsigned)((q + 1) & 2) << 30;
    s = __uint_as_float(__float_as_uint(s0) ^ sgn_s);
    c = __uint_as_float(__float_as_uint(c0) ^ sgn_c);
}

// a = a ⊗ elem(theta=(ax,ay,az), l).  R = Rz@Ry@Rx (ZYX Euler).
__device__ __forceinline__ void xf_fold(Xf& a, float ax, float ay, float az, float l) {
    float sx, cx, sy, cy, sz, cz;
    fast_sincos(ax, sx, cx);
    fast_sincos(ay, sy, cy);
    fast_sincos(az, sz, cz);
    const float sysx = sy * sx, sycx = sy * cx;
    const float r00 = cz * cy;
    const float r01 = cz * sysx - sz * cx;
    const float r02 = sz * sx + cz * sycx;
    const float r10 = sz * cy;
    const float r11 = cz * cx + sz * sysx;
    const float r12 = sz * sycx - cz * sx;
    const float r20 = -sy;
    const float r21 = cy * sx;
    const float r22 = cy * cx;
    const float t0 = l * r02, t1 = l * r12, t2 = l * r22;
    const float p0 = a.p[0] + a.m[0] * t0 + a.m[1] * t1 + a.m[2] * t2;
    const float p1 = a.p[1] + a.m[3] * t0 + a.m[4] * t1 + a.m[5] * t2;
    const float p2 = a.p[2] + a.m[6] * t0 + a.m[7] * t1 + a.m[8] * t2;
    const float n0 = a.m[0] * r00 + a.m[1] * r10 + a.m[2] * r20;
    const float n1 = a.m[0] * r01 + a.m[1] * r11 + a.m[2] * r21;
    const float n2 = a.m[0] * r02 + a.m[1] * r12 + a.m[2] * r22;
    const float n3 = a.m[3] * r00 + a.m[4] * r10 + a.m[5] * r20;
    const float n4 = a.m[3] * r01 + a.m[4] * r11 + a.m[5] * r21;
    const float n5 = a.m[3] * r02 + a.m[4] * r12 + a.m[5] * r22;
    const float n6 = a.m[6] * r00 + a.m[7] * r10 + a.m[8] * r20;
    const float n7 = a.m[6] * r01 + a.m[7] * r11 + a.m[8] * r21;
    const float n8 = a.m[6] * r02 + a.m[7] * r12 + a.m[8] * r22;
    a.m[0] = n0; a.m[1] = n1; a.m[2] = n2;
    a.m[3] = n3; a.m[4] = n4; a.m[5] = n5;
    a.m[6] = n6; a.m[7] = n7; a.m[8] = n8;
    a.p[0] = p0; a.p[1] = p1; a.p[2] = p2;
}

// ---- wave shuffle helpers ----
__device__ __forceinline__ Xf xf_shfl_up(const Xf& a, int delta) {
    Xf o;
#pragma unroll
    for (int k = 0; k < 9; ++k) o.m[k] = __shfl_up(a.m[k], delta, 64);
#pragma unroll
    for (int k = 0; k < 3; ++k) o.p[k] = __shfl_up(a.p[k], delta, 64);
    return o;
}
__device__ __forceinline__ Xf xf_shfl_down(const Xf& a, int delta) {
    Xf o;
#pragma unroll
    for (int k = 0; k < 9; ++k) o.m[k] = __shfl_down(a.m[k], delta, 64);
#pragma unroll
    for (int k = 0; k < 3; ++k) o.p[k] = __shfl_down(a.p[k], delta, 64);
    return o;
}

// Inclusive scan across the 64-lane wave.
__device__ __forceinline__ Xf wave_scan(Xf a, int lane) {
#pragma unroll
    for (int off = 1; off < 64; off <<= 1) {
        const Xf b = xf_shfl_up(a, off);
        if (lane >= off) a = xf_comb(b, a);
    }
    return a;
}

// Ordered wave reduce: lane 0 ends with v_0 ⊗ v_1 ⊗ ... ⊗ v_63.
__device__ __forceinline__ Xf wave_reduce(Xf v, int lane) {
#pragma unroll
    for (int off = 1; off < 64; off <<= 1) {
        const Xf b = xf_shfl_down(v, off);
        if (lane + off < 64) v = xf_comb(v, b);
    }
    return v;
}

// ---- Xf <-> global as 3x float4 ----
__device__ __forceinline__ Xf xf_load4(const Xf* p) {
    const float4* g = (const float4*)p;
    const float4 x = g[0], y = g[1], z = g[2];
    Xf b;
    b.m[0] = x.x; b.m[1] = x.y; b.m[2] = x.z;
    b.m[3] = x.w; b.m[4] = y.x; b.m[5] = y.y;
    b.m[6] = y.z; b.m[7] = y.w; b.m[8] = z.x;
    b.p[0] = z.y; b.p[1] = z.z; b.p[2] = z.w;
    return b;
}
__device__ __forceinline__ void xf_store4(Xf* p, const Xf& b) {
    float4* g = (float4*)p;
    g[0] = make_float4(b.m[0], b.m[1], b.m[2], b.m[3]);
    g[1] = make_float4(b.m[4], b.m[5], b.m[6], b.m[7]);
    g[2] = make_float4(b.m[8], b.p[0], b.p[1], b.p[2]);
}

// apply affine T to point q
__device__ __forceinline__ void xf_apply(const Xf& T, float q0, float q1, float q2,
                                         float& o0, float& o1, float& o2) {
    o0 = T.p[0] + T.m[0] * q0 + T.m[1] * q1 + T.m[2] * q2;
    o1 = T.p[1] + T.m[3] * q0 + T.m[4] * q1 + T.m[5] * q2;
    o2 = T.p[2] + T.m[6] * q0 + T.m[7] * q1 + T.m[8] * q2;
}

// ---- local fold of E elements, recording per-element positions ----
template <int E>
__device__ __forceinline__ void local_fold(const float* __restrict__ ll,
                                           const float* __restrict__ th,
                                           long long j0, int n, Xf& a,
                                           float pe[E][3]) {
    xf_identity(a);
    if (j0 + E <= n) {
        if constexpr (E == 4) {
            const float4* th4 = (const float4*)(th + 3 * j0);
            const float4 A = th4[0], B = th4[1], C = th4[2];
            const float4 L = *(const float4*)(ll + j0);
            xf_fold(a, A.x, A.y, A.z, L.x);
            pe[0][0] = a.p[0]; pe[0][1] = a.p[1]; pe[0][2] = a.p[2];
            xf_fold(a, A.w, B.x, B.y, L.y);
            pe[1][0] = a.p[0]; pe[1][1] = a.p[1]; pe[1][2] = a.p[2];
            xf_fold(a, B.z, B.w, C.x, L.z);
            pe[2][0] = a.p[0]; pe[2][1] = a.p[1]; pe[2][2] = a.p[2];
            xf_fold(a, C.y, C.z, C.w, L.w);
            pe[3][0] = a.p[0]; pe[3][1] = a.p[1]; pe[3][2] = a.p[2];
        } else {
            const float2* th2 = (const float2*)(th + 3 * j0);
            const float2 d0 = th2[0], d1 = th2[1], d2 = th2[2];
            const float2 L = *(const float2*)(ll + j0);
            xf_fold(a, d0.x, d0.y, d1.x, L.x);
            pe[0][0] = a.p[0]; pe[0][1] = a.p[1]; pe[0][2] = a.p[2];
            xf_fold(a, d1.y, d2.x, d2.y, L.y);
            pe[1][0] = a.p[0]; pe[1][1] = a.p[1]; pe[1][2] = a.p[2];
        }
    } else {
#pragma unroll
        for (int e = 0; e < E; ++e) {
            const long long j = j0 + e;
            if (j < n) xf_fold(a, th[3 * j + 0], th[3 * j + 1], th[3 * j + 2], ll[j]);
            pe[e][0] = a.p[0]; pe[e][1] = a.p[1]; pe[e][2] = a.p[2];
        }
    }
}

// ================= R7: single cooperative kernel =================
__global__ void __launch_bounds__(TPB, 4)
fk_coop(const float* __restrict__ ll, const float* __restrict__ th,
        Xf* __restrict__ agg, float* __restrict__ out, int n) {
    __shared__ Xf wagg[NWAVE];
    __shared__ Xf shG;
    const int t = threadIdx.x, bid = blockIdx.x;
    const int lane = t & 63, w = t >> 6;
    const long long j0 = (long long)bid * EPB + (long long)t * EPT;

    // 1. local fold + block scan (pe stays in registers)
    Xf a;
    float pe[EPT][3];
    local_fold<EPT>(ll, th, j0, n, a, pe);

    const Xf inc = wave_scan(a, lane);
    if (lane == 63) wagg[w] = inc;
    __syncthreads();

    Xf exw;  // cross-wave exclusive prefix (broadcast LDS reads)
    xf_identity(exw);
    for (int k = 0; k < w; ++k) exw = xf_comb(exw, wagg[k]);

    if (t == TPB - 1) xf_store4(&agg[bid], xf_comb(exw, inc));  // block aggregate

    const Xf ext = xf_shfl_up(inc, 1);
    Xf T = exw;
    if (lane != 0) T = xf_comb(T, ext);

    // block-local inclusive positions, in registers
    float q[EPT][3];
#pragma unroll
    for (int e = 0; e < EPT; ++e)
        xf_apply(T, pe[e][0], pe[e][1], pe[e][2], q[e][0], q[e][1], q[e][2]);

    // 2. grid-wide sync (agg stores become visible)
    cg::this_grid().sync();

    // 3. redundant per-block ordered G-reduce: G = agg[0] ⊗ ... ⊗ agg[bid-1]
    {
        const int i0 = t * EPT;
        Xf A;
        xf_identity(A);
#pragma unroll
        for (int e = 0; e < EPT; ++e) {
            const int i = i0 + e;
            if (i < bid) A = xf_comb(A, xf_load4(&agg[i]));
        }
        const Xf red = wave_reduce(A, lane);
        if (lane == 0) wagg[w] = red;  // reuse (grid sync included block barrier)
    }
    __syncthreads();
    if (t == 0) {
        Xf G = wagg[0];
#pragma unroll
        for (int k = 1; k < NWAVE; ++k) G = xf_comb(G, wagg[k]);
        shG = G;
    }
    __syncthreads();
    const Xf G = shG;

    // 4. out = G(q), single coalesced write
    if (j0 + EPT <= n) {
        float o[EPT * 3];
#pragma unroll
        for (int e = 0; e < EPT; ++e)
            xf_apply(G, q[e][0], q[e][1], q[e][2], o[e * 3 + 0], o[e * 3 + 1], o[e * 3 + 2]);
        float4* o4 = (float4*)(out + 3 * j0);
        o4[0] = make_float4(o[0], o[1], o[2], o[3]);
        o4[1] = make_float4(o[4], o[5], o[6], o[7]);
        o4[2] = make_float4(o[8], o[9], o[10], o[11]);
    } else {
#pragma unroll
        for (int e = 0; e < EPT; ++e) {
            const long long j = j0 + e;
            if (j < n) {
                float o0, o1, o2;
                xf_apply(G, q[e][0], q[e][1], q[e][2], o0, o1, o2);
                out[3 * j + 0] = o0; out[3 * j + 1] = o1; out[3 * j + 2] = o2;
            }
        }
    }
}

// ================= fallback: R6 two-kernel path =================
__global__ void __launch_bounds__(K1_TPB, 6)
fk_local(const float* __restrict__ ll, const float* __restrict__ th,
         Xf* __restrict__ agg, float* __restrict__ out, int n) {
    __shared__ Xf wagg[K1_NW];
    const int t = threadIdx.x, bid = blockIdx.x;
    const int lane = t & 63, w = t >> 6;
    const long long j0 = (long long)bid * K1_EPB + (long long)t * K1_EPT;

    Xf a;
    float pe[K1_EPT][3];
    local_fold<K1_EPT>(ll, th, j0, n, a, pe);

    const Xf inc = wave_scan(a, lane);
    if (lane == 63) wagg[w] = inc;
    __syncthreads();

    Xf exw;
    xf_identity(exw);
    for (int k = 0; k < w; ++k) exw = xf_comb(exw, wagg[k]);

    if (t == K1_TPB - 1) xf_store4(&agg[bid], xf_comb(exw, inc));

    const Xf ext = xf_shfl_up(inc, 1);
    Xf T = exw;
    if (lane != 0) T = xf_comb(T, ext);

    if (j0 + K1_EPT <= n) {
        float o0, o1, o2, o3, o4, o5;
        xf_apply(T, pe[0][0], pe[0][1], pe[0][2], o0, o1, o2);
        xf_apply(T, pe[1][0], pe[1][1], pe[1][2], o3, o4, o5);
        float2* q2 = (float2*)(out + 3 * j0);
        q2[0] = make_float2(o0, o1);
        q2[1] = make_float2(o2, o3);
        q2[2] = make_float2(o4, o5);
    } else {
#pragma unroll
        for (int e = 0; e < K1_EPT; ++e) {
            const long long j = j0 + e;
            if (j < n) {
                float o0, o1, o2;
                xf_apply(T, pe[e][0], pe[e][1], pe[e][2], o0, o1, o2);
                out[3 * j + 0] = o0; out[3 * j + 1] = o1; out[3 * j + 2] = o2;
            }
        }
    }
}

__global__ void __launch_bounds__(TPB)
fk_fixup(const Xf* __restrict__ agg, float* __restrict__ out, int n, int nb) {
    __shared__ Xf wred[NWAVE];
    __shared__ Xf shG;
    const int t = threadIdx.x, bid = blockIdx.x;
    const int lane = t & 63, w = t >> 6;

    {
        const int i0 = t * EPT;
        Xf A;
        xf_identity(A);
#pragma unroll
        for (int e = 0; e < EPT; ++e) {
            const int i = i0 + e;
            if (i < bid) A = xf_comb(A, xf_load4(&agg[i]));
        }
        const Xf red = wave_reduce(A, lane);
        if (lane == 0) wred[w] = red;
    }
    __syncthreads();
    if (t == 0) {
        Xf G = wred[0];
#pragma unroll
        for (int k = 1; k < NWAVE; ++k) G = xf_comb(G, wred[k]);
        shG = G;
    }
    __syncthreads();
    const Xf G = shG;

    const long long j0 = (long long)bid * EPB + (long long)t * EPT;
    if (j0 + EPT <= n) {
        float4* o4 = (float4*)(out + 3 * j0);
        const float4 x = o4[0], y = o4[1], z = o4[2];
        float r[12];
        xf_apply(G, x.x, x.y, x.z, r[0], r[1], r[2]);
        xf_apply(G, x.w, y.x, y.y, r[3], r[4], r[5]);
        xf_apply(G, y.z, y.w, z.x, r[6], r[7], r[8]);
        xf_apply(G, z.y, z.z, z.w, r[9], r[10], r[11]);
        o4[0] = make_float4(r[0], r[1], r[2], r[3]);
        o4[1] = make_float4(r[4], r[5], r[6], r[7]);
        o4[2] = make_float4(r[8], r[9], r[10], r[11]);
    } else {
#pragma unroll
        for (int e = 0; e < EPT; ++e) {
            const long long j = j0 + e;
            if (j < n) {
                float o0, o1, o2;
                xf_apply(G, out[3 * j + 0], out[3 * j + 1], out[3 * j + 2], o0, o1, o2);
                out[3 * j + 0] = o0; out[3 * j + 1] = o1; out[3 * j + 2] = o2;
            }
        }
    }
}

extern "C" void kernel_launch(void* const* d_in, const int* in_sizes, int n_in,
                              void* d_out, int out_size, void* d_ws, size_t ws_size,
                              hipStream_t stream) {
    const float* ll = (const float*)d_in[0];   // link_lengths [N]
    const float* th = (const float*)d_in[1];   // theta [N,3]
    float* out = (float*)d_out;                // [N,3] f32
    int n = in_sizes[0];

    int nb = (n + EPB - 1) / EPB;              // 1024 for N = 2^20
    if (nb > MAXB) nb = MAXB;

    Xf* agg = (Xf*)d_ws;                       // 48 KB

    void* args[] = {(void*)&ll, (void*)&th, (void*)&agg, (void*)&out, (void*)&n};
    hipError_t err = hipLaunchCooperativeKernel((const void*)fk_coop, dim3(nb), dim3(TPB),
                                                args, 0, stream);
    if (err != hipSuccess) {
        int nb1 = (n + K1_EPB - 1) / K1_EPB;
        if (nb1 > MAXB) nb1 = MAXB;
        fk_local<<<nb1, K1_TPB, 0, stream>>>(ll, th, agg, out, n);
        fk_fixup<<<nb, TPB, 0, stream>>>(agg, out, n, nb);
    }
}

// Round 9
// 29.771 us; speedup vs baseline: 3.1939x; 3.1939x over previous
//
#include <hip/hip_runtime.h>
#include <math.h>

// Forward kinematics as an associative scan over affine pairs (M, p):
//   elem_j = (R_j, l_j * R_j[:,2]);  (M1,p1) ⊗ (M2,p2) = (M1*M2, p1 + M1*p2)
// Output_i = p-component of inclusive prefix up to i.
//
// R8: two-kernel scan (coop grid.sync costs ~60us on MI355X - R2/R7; lookback
// flag-spin costs ~100us - R4). K1: fold -> DPP wave scan -> block aggregate.
// K2: redundant per-block ordered G-reduce of aggregates (DPP) + fold with
// positions + DPP wave scan + apply + write. The DPP scan (row_shr 1/2/4/8 +
// row_bcast 15/31, identity fill via update_dpp's old) replaces the
// ds_bpermute shuffle scan: zero DS-pipe traffic, ~5cyc/step latency.
// fast_sincos (~2ulp, Cody-Waite + cephes) validated in R7 (absmax 4.0).

#define TPB 256
#define EPT 4
#define EPB (TPB * EPT)            // 1024 elements per block
#define MAXB 1024                  // blocks for N = 2^20
#define NWAVE (TPB / 64)

struct Xf {
    float m[9];  // row-major 3x3
    float p[3];
};

__device__ __forceinline__ void xf_identity(Xf& x) {
    x.m[0] = 1.f; x.m[1] = 0.f; x.m[2] = 0.f;
    x.m[3] = 0.f; x.m[4] = 1.f; x.m[5] = 0.f;
    x.m[6] = 0.f; x.m[7] = 0.f; x.m[8] = 1.f;
    x.p[0] = 0.f; x.p[1] = 0.f; x.p[2] = 0.f;
}

// out = A ⊗ B  (A is the earlier prefix)
__device__ __forceinline__ Xf xf_comb(const Xf& A, const Xf& B) {
    Xf o;
#pragma unroll
    for (int r = 0; r < 3; ++r) {
        const float a0 = A.m[r * 3 + 0], a1 = A.m[r * 3 + 1], a2 = A.m[r * 3 + 2];
#pragma unroll
        for (int c = 0; c < 3; ++c) {
            o.m[r * 3 + c] = a0 * B.m[0 * 3 + c] + a1 * B.m[1 * 3 + c] + a2 * B.m[2 * 3 + c];
        }
        o.p[r] = A.p[r] + a0 * B.p[0] + a1 * B.p[1] + a2 * B.p[2];
    }
    return o;
}

// ---- fast ~2ulp sincos, valid |x| <= ~12 (theta ~ N(0,1)) ----
__device__ __forceinline__ void fast_sincos(float x, float& s, float& c) {
    const float fn = __builtin_rintf(x * 0.636619772367581343f);  // 2/pi
    const int n = (int)fn;
    float r = __builtin_fmaf(fn, -1.57079637050628662109375f, x); // -pio2_hi
    r = __builtin_fmaf(fn, 4.37113900018624283e-8f, r);           // -pio2_mid
    const float r2 = r * r;
    float sp = __builtin_fmaf(r2, -1.9515295891e-4f, 8.3321608736e-3f);
    sp = __builtin_fmaf(r2, sp, -1.6666654611e-1f);
    const float ss = __builtin_fmaf(r * r2, sp, r);               // sin(r)
    float cp = __builtin_fmaf(r2, 2.443315711809948e-5f, -1.388731625493765e-3f);
    cp = __builtin_fmaf(r2, cp, 4.166664568298827e-2f);
    const float cc = __builtin_fmaf(r2 * r2, cp,
                                    __builtin_fmaf(r2, -0.5f, 1.0f));  // cos(r)
    const int q = n & 3;
    const float s0 = (q & 1) ? cc : ss;
    const float c0 = (q & 1) ? ss : cc;
    const unsigned sgn_s = (unsigned)(q & 2) << 30;
    const unsigned sgn_c = (unsigned)((q + 1) & 2) << 30;
    s = __uint_as_float(__float_as_uint(s0) ^ sgn_s);
    c = __uint_as_float(__float_as_uint(c0) ^ sgn_c);
}

// a = a ⊗ elem(theta=(ax,ay,az), l).  R = Rz@Ry@Rx (ZYX Euler).
__device__ __forceinline__ void xf_fold(Xf& a, float ax, float ay, float az, float l) {
    float sx, cx, sy, cy, sz, cz;
    fast_sincos(ax, sx, cx);
    fast_sincos(ay, sy, cy);
    fast_sincos(az, sz, cz);
    const float sysx = sy * sx, sycx = sy * cx;
    const float r00 = cz * cy;
    const float r01 = cz * sysx - sz * cx;
    const float r02 = sz * sx + cz * sycx;
    const float r10 = sz * cy;
    const float r11 = cz * cx + sz * sysx;
    const float r12 = sz * sycx - cz * sx;
    const float r20 = -sy;
    const float r21 = cy * sx;
    const float r22 = cy * cx;
    const float t0 = l * r02, t1 = l * r12, t2 = l * r22;
    const float p0 = a.p[0] + a.m[0] * t0 + a.m[1] * t1 + a.m[2] * t2;
    const float p1 = a.p[1] + a.m[3] * t0 + a.m[4] * t1 + a.m[5] * t2;
    const float p2 = a.p[2] + a.m[6] * t0 + a.m[7] * t1 + a.m[8] * t2;
    const float n0 = a.m[0] * r00 + a.m[1] * r10 + a.m[2] * r20;
    const float n1 = a.m[0] * r01 + a.m[1] * r11 + a.m[2] * r21;
    const float n2 = a.m[0] * r02 + a.m[1] * r12 + a.m[2] * r22;
    const float n3 = a.m[3] * r00 + a.m[4] * r10 + a.m[5] * r20;
    const float n4 = a.m[3] * r01 + a.m[4] * r11 + a.m[5] * r21;
    const float n5 = a.m[3] * r02 + a.m[4] * r12 + a.m[5] * r22;
    const float n6 = a.m[6] * r00 + a.m[7] * r10 + a.m[8] * r20;
    const float n7 = a.m[6] * r01 + a.m[7] * r11 + a.m[8] * r21;
    const float n8 = a.m[6] * r02 + a.m[7] * r12 + a.m[8] * r22;
    a.m[0] = n0; a.m[1] = n1; a.m[2] = n2;
    a.m[3] = n3; a.m[4] = n4; a.m[5] = n5;
    a.m[6] = n6; a.m[7] = n7; a.m[8] = n8;
    a.p[0] = p0; a.p[1] = p1; a.p[2] = p2;
}

// ---- DPP wave scan (gfx9 pattern): 6 VALU rounds, no DS, no divergence ----
// row_shr:N = 0x110|N ; row_bcast:15 = 0x142 ; row_bcast:31 = 0x143
template <int CTRL, int RMASK>
__device__ __forceinline__ float dpp_f(float src, float oldv) {
    return __int_as_float(__builtin_amdgcn_update_dpp(
        __float_as_int(oldv), __float_as_int(src), CTRL, RMASK, 0xF, false));
}

template <int CTRL, int RMASK>
__device__ __forceinline__ Xf xf_scan_step(const Xf& v) {
    Xf b;
    b.m[0] = dpp_f<CTRL, RMASK>(v.m[0], 1.f);
    b.m[1] = dpp_f<CTRL, RMASK>(v.m[1], 0.f);
    b.m[2] = dpp_f<CTRL, RMASK>(v.m[2], 0.f);
    b.m[3] = dpp_f<CTRL, RMASK>(v.m[3], 0.f);
    b.m[4] = dpp_f<CTRL, RMASK>(v.m[4], 1.f);
    b.m[5] = dpp_f<CTRL, RMASK>(v.m[5], 0.f);
    b.m[6] = dpp_f<CTRL, RMASK>(v.m[6], 0.f);
    b.m[7] = dpp_f<CTRL, RMASK>(v.m[7], 0.f);
    b.m[8] = dpp_f<CTRL, RMASK>(v.m[8], 1.f);
    b.p[0] = dpp_f<CTRL, RMASK>(v.p[0], 0.f);
    b.p[1] = dpp_f<CTRL, RMASK>(v.p[1], 0.f);
    b.p[2] = dpp_f<CTRL, RMASK>(v.p[2], 0.f);
    return xf_comb(b, v);  // b = earlier prefix (or identity)
}

// Inclusive scan across the 64-lane wave, pure VALU.
__device__ __forceinline__ Xf wave_scan(Xf v) {
    v = xf_scan_step<0x111, 0xF>(v);  // row_shr:1
    v = xf_scan_step<0x112, 0xF>(v);  // row_shr:2
    v = xf_scan_step<0x114, 0xF>(v);  // row_shr:4
    v = xf_scan_step<0x118, 0xF>(v);  // row_shr:8  -> row-local inclusive
    v = xf_scan_step<0x142, 0xA>(v);  // row_bcast:15 -> rows 1,3
    v = xf_scan_step<0x143, 0xC>(v);  // row_bcast:31 -> rows 2,3
    return v;
}

// thread-exclusive within wave (single bpermute-based shuffle, 12 ops)
__device__ __forceinline__ Xf xf_shfl_up1(const Xf& a) {
    Xf o;
#pragma unroll
    for (int k = 0; k < 9; ++k) o.m[k] = __shfl_up(a.m[k], 1, 64);
#pragma unroll
    for (int k = 0; k < 3; ++k) o.p[k] = __shfl_up(a.p[k], 1, 64);
    return o;
}

// ---- Xf <-> global as 3x float4 ----
__device__ __forceinline__ Xf xf_load4(const Xf* p) {
    const float4* g = (const float4*)p;
    const float4 x = g[0], y = g[1], z = g[2];
    Xf b;
    b.m[0] = x.x; b.m[1] = x.y; b.m[2] = x.z;
    b.m[3] = x.w; b.m[4] = y.x; b.m[5] = y.y;
    b.m[6] = y.z; b.m[7] = y.w; b.m[8] = z.x;
    b.p[0] = z.y; b.p[1] = z.z; b.p[2] = z.w;
    return b;
}
__device__ __forceinline__ void xf_store4(Xf* p, const Xf& b) {
    float4* g = (float4*)p;
    g[0] = make_float4(b.m[0], b.m[1], b.m[2], b.m[3]);
    g[1] = make_float4(b.m[4], b.m[5], b.m[6], b.m[7]);
    g[2] = make_float4(b.m[8], b.p[0], b.p[1], b.p[2]);
}

// apply affine T to point q
__device__ __forceinline__ void xf_apply(const Xf& T, float q0, float q1, float q2,
                                         float& o0, float& o1, float& o2) {
    o0 = T.p[0] + T.m[0] * q0 + T.m[1] * q1 + T.m[2] * q2;
    o1 = T.p[1] + T.m[3] * q0 + T.m[4] * q1 + T.m[5] * q2;
    o2 = T.p[2] + T.m[6] * q0 + T.m[7] * q1 + T.m[8] * q2;
}

// ---- local fold of EPT elements ----
__device__ __forceinline__ void local_fold(const float* __restrict__ ll,
                                           const float* __restrict__ th,
                                           long long j0, int n, Xf& a,
                                           float pe[EPT][3], bool record) {
    xf_identity(a);
    if (j0 + EPT <= n) {
        const float4* th4 = (const float4*)(th + 3 * j0);
        const float4 A = th4[0], B = th4[1], C = th4[2];
        const float4 L = *(const float4*)(ll + j0);
        xf_fold(a, A.x, A.y, A.z, L.x);
        if (record) { pe[0][0] = a.p[0]; pe[0][1] = a.p[1]; pe[0][2] = a.p[2]; }
        xf_fold(a, A.w, B.x, B.y, L.y);
        if (record) { pe[1][0] = a.p[0]; pe[1][1] = a.p[1]; pe[1][2] = a.p[2]; }
        xf_fold(a, B.z, B.w, C.x, L.z);
        if (record) { pe[2][0] = a.p[0]; pe[2][1] = a.p[1]; pe[2][2] = a.p[2]; }
        xf_fold(a, C.y, C.z, C.w, L.w);
        if (record) { pe[3][0] = a.p[0]; pe[3][1] = a.p[1]; pe[3][2] = a.p[2]; }
    } else {
#pragma unroll
        for (int e = 0; e < EPT; ++e) {
            const long long j = j0 + e;
            if (j < n) xf_fold(a, th[3 * j + 0], th[3 * j + 1], th[3 * j + 2], ll[j]);
            if (record) { pe[e][0] = a.p[0]; pe[e][1] = a.p[1]; pe[e][2] = a.p[2]; }
        }
    }
}

// ---------------- K1: per-block aggregates ----------------
__global__ void __launch_bounds__(TPB, 4)
fk_agg(const float* __restrict__ ll, const float* __restrict__ th,
       Xf* __restrict__ agg, int n) {
    __shared__ Xf wagg[NWAVE];
    const int t = threadIdx.x;
    const int lane = t & 63, w = t >> 6;
    const long long j0 = (long long)blockIdx.x * EPB + (long long)t * EPT;

    Xf a;
    float pe[EPT][3];
    local_fold(ll, th, j0, n, a, pe, false);

    const Xf inc = wave_scan(a);
    if (lane == 63) wagg[w] = inc;
    __syncthreads();

    if (t == 0) {
        Xf acc = wagg[0];
#pragma unroll
        for (int k = 1; k < NWAVE; ++k) acc = xf_comb(acc, wagg[k]);
        xf_store4(&agg[blockIdx.x], acc);
    }
}

// ---------------- K2: G-reduce + fold + scan + apply + write ----------------
__global__ void __launch_bounds__(TPB, 4)
fk_apply(const float* __restrict__ ll, const float* __restrict__ th,
         const Xf* __restrict__ agg, float* __restrict__ out, int n) {
    __shared__ Xf wred[NWAVE];
    __shared__ Xf wagg[NWAVE];
    __shared__ Xf shG;
    const int t = threadIdx.x, bid = blockIdx.x;
    const int lane = t & 63, w = t >> 6;
    const long long j0 = (long long)bid * EPB + (long long)t * EPT;

    // 1. G = agg[0] ⊗ ... ⊗ agg[bid-1], cooperatively, ordered
    {
        const int i0 = t * EPT;
        Xf A;
        xf_identity(A);
#pragma unroll
        for (int e = 0; e < EPT; ++e) {
            const int i = i0 + e;
            if (i < bid) A = xf_comb(A, xf_load4(&agg[i]));
        }
        const Xf inc = wave_scan(A);
        if (lane == 63) wred[w] = inc;
    }
    __syncthreads();
    if (t == 0) {
        Xf G = wred[0];
#pragma unroll
        for (int k = 1; k < NWAVE; ++k) G = xf_comb(G, wred[k]);
        shG = G;
    }

    // 2. local fold + wave scan
    Xf a;
    float pe[EPT][3];
    local_fold(ll, th, j0, n, a, pe, true);

    const Xf inc = wave_scan(a);
    if (lane == 63) wagg[w] = inc;
    __syncthreads();

    Xf exw;  // cross-wave exclusive prefix (broadcast LDS reads)
    xf_identity(exw);
    for (int k = 0; k < w; ++k) exw = xf_comb(exw, wagg[k]);

    const Xf ext = xf_shfl_up1(inc);

    Xf T = xf_comb(shG, exw);
    if (lane != 0) T = xf_comb(T, ext);

    // 3. out = T(pe)
    if (j0 + EPT <= n) {
        float o[EPT * 3];
#pragma unroll
        for (int e = 0; e < EPT; ++e)
            xf_apply(T, pe[e][0], pe[e][1], pe[e][2],
                     o[e * 3 + 0], o[e * 3 + 1], o[e * 3 + 2]);
        float4* o4 = (float4*)(out + 3 * j0);
        o4[0] = make_float4(o[0], o[1], o[2], o[3]);
        o4[1] = make_float4(o[4], o[5], o[6], o[7]);
        o4[2] = make_float4(o[8], o[9], o[10], o[11]);
    } else {
#pragma unroll
        for (int e = 0; e < EPT; ++e) {
            const long long j = j0 + e;
            if (j < n) {
                float o0, o1, o2;
                xf_apply(T, pe[e][0], pe[e][1], pe[e][2], o0, o1, o2);
                out[3 * j + 0] = o0; out[3 * j + 1] = o1; out[3 * j + 2] = o2;
            }
        }
    }
}

extern "C" void kernel_launch(void* const* d_in, const int* in_sizes, int n_in,
                              void* d_out, int out_size, void* d_ws, size_t ws_size,
                              hipStream_t stream) {
    const float* ll = (const float*)d_in[0];   // link_lengths [N]
    const float* th = (const float*)d_in[1];   // theta [N,3]
    float* out = (float*)d_out;                // [N,3] f32
    const int n = in_sizes[0];

    int nb = (n + EPB - 1) / EPB;              // 1024 for N = 2^20
    if (nb > MAXB) nb = MAXB;

    Xf* agg = (Xf*)d_ws;                       // 48 KB

    fk_agg<<<nb, TPB, 0, stream>>>(ll, th, agg, n);
    fk_apply<<<nb, TPB, 0, stream>>>(ll, th, agg, out, n);
}